// Round 3
// baseline (111.533 us; speedup 1.0000x reference)
//
#include <hip/hip_runtime.h>
#include <cmath>

#define B_N 8192
#define D_K 128
#define ROWS 128           // rows per block; wave w owns rows [w*32, +32) = 2 row-tiles
#define CSPLIT 16          // column splits; block covers 512 cols
#define T_OUT 8            // 64-col super-tiles per block: 512/64 (fp8: 8KB stage)

typedef float f32x4 __attribute__((ext_vector_type(4)));
typedef long  lx2   __attribute__((ext_vector_type(2)));

typedef __attribute__((address_space(3))) unsigned int as3_uint;
typedef __attribute__((address_space(1))) unsigned int as1_uint;

// Async global->LDS DMA, 16 B/lane. HW dest = wave-uniform base + lane*16
// (pattern correctness-verified R9-R13, absmax 0.0).
__device__ __forceinline__ void gl_lds16(const void* g, void* l) {
    __builtin_amdgcn_global_load_lds((const as1_uint*)(uintptr_t)g,
                                     (as3_uint*)(unsigned int)(uintptr_t)l,
                                     16, 0, 0);
}

// Convert fp32 Q and A to fp8 e4m3 (OCP, via v_cvt_pk_fp8_f32 — R7-verified,
// absmax 2.4e-4). Q: row-major fp8 (byte g*8). A: packed for 16x16x32 fp8 B-op:
// per 16-col tile T, k-pair p in {0,1}: 1 KB region at T*2048 + p*1024; lane
// L = quad*16+e holds 16 B at L*16 = A[col=T*16+e][k=(2p)*32+quad*8..+7] ++
// A[col][k=(2p+1)*32+quad*8..+7]. Stages are contiguous 8 KB (4-tile) pieces.
// Also zeroes d_out (harness re-poisons to 0xAA before every replay).
__global__ void cvt_kernel(const float* __restrict__ q, const float* __restrict__ a,
                           unsigned char* __restrict__ qp, unsigned char* __restrict__ ap,
                           float* __restrict__ out) {
    const int g = blockIdx.x * blockDim.x + threadIdx.x;   // 0 .. B*D/8-1
    if (g < 2) out[g] = 0.0f;

    float4 q0 = reinterpret_cast<const float4*>(q)[g * 2];
    float4 q1 = reinterpret_cast<const float4*>(q)[g * 2 + 1];
    float4 a0 = reinterpret_cast<const float4*>(a)[g * 2];
    float4 a1 = reinterpret_cast<const float4*>(a)[g * 2 + 1];

    int qw0 = __builtin_amdgcn_cvt_pk_fp8_f32(q0.x, q0.y, 0, false);
    qw0     = __builtin_amdgcn_cvt_pk_fp8_f32(q0.z, q0.w, qw0, true);
    int qw1 = __builtin_amdgcn_cvt_pk_fp8_f32(q1.x, q1.y, 0, false);
    qw1     = __builtin_amdgcn_cvt_pk_fp8_f32(q1.z, q1.w, qw1, true);
    int aw0 = __builtin_amdgcn_cvt_pk_fp8_f32(a0.x, a0.y, 0, false);
    aw0     = __builtin_amdgcn_cvt_pk_fp8_f32(a0.z, a0.w, aw0, true);
    int aw1 = __builtin_amdgcn_cvt_pk_fp8_f32(a1.x, a1.y, 0, false);
    aw1     = __builtin_amdgcn_cvt_pk_fp8_f32(a1.z, a1.w, aw1, true);

    // Q row-major fp8
    *reinterpret_cast<int2*>(qp + (size_t)g * 8) = make_int2(qw0, qw1);

    // A fragment-packed fp8
    const int col = g >> 4, sq = g & 15;       // k = sq*8 .. +7
    const int s = sq >> 2, quad = sq & 3;      // k-step of 32, quad within step
    const int T = col >> 4, e = col & 15;
    const size_t off = (size_t)T * 2048 + (size_t)(s >> 1) * 1024
                     + (size_t)(quad * 16 + e) * 16 + (size_t)(s & 1) * 8;
    *reinterpret_cast<int2*>(ap + off) = make_int2(aw0, aw1);
}

// Block (rg, cs): rows [rg*128,+128) over cols [cs*512,+512). 4 waves; wave w
// owns rows [rg*128 + w*32, +32) = TWO 16-row tiles. All waves sweep the same
// cols via LDS-shared B-tiles.
// R3 vs R0(95.5µs): each B-fragment ds_read now feeds 8 MFMAs (2 row-tiles)
// instead of 4 -> LDS-read pipe floor halves (~10 -> ~5 µs/CU). MFMAs/barrier
// stays 32 (R0's value; R2's halving to 16 was the suspected regression).
// Grid stays 1024 (4 blocks/CU), LDS 16 KB, staging byte-identical to R2
// (absmax-verified). Per-element epilogue math/order unchanged.
// MFMA 16x16x32 fp8_fp8 (R7-verified lane mapping):
//   A-op: lane holds A[m=lane&15][k=(lane>>4)*8+j] (8 B); B-op transposed same;
//   C/D : col=lane&15, row=(lane>>4)*4+reg.
// Sentinels: VGPR ~85-100 (<=128, NO scratch), WRITE_SIZE ~2 MB, bank conflicts ~0.
__launch_bounds__(256, 4)
__global__ void mpl_part_kernel(const unsigned char* __restrict__ qp,
                                const unsigned char* __restrict__ ap,
                                const int* __restrict__ qids,
                                const float* __restrict__ ranks,
                                float* __restrict__ pden, float* __restrict__ pnum,
                                float* __restrict__ pmax, float* __restrict__ pmaxp) {
    __shared__ unsigned char smem[2 * 8192];   // 2 x 8 KB

    const int tid  = threadIdx.x;
    const int lane = tid & 63;
    const int wave = tid >> 6;               // 0..3
    const int rg   = blockIdx.x >> 4;        // 0..63
    const int cs   = blockIdx.x & 15;        // 0..15 (cs&7 == XCD id under %8 dispatch)
    const int rowBaseW = rg * ROWS + wave * 32;   // this wave's 32-row window
    const int quad = lane >> 4;              // 0..3
    const int l15  = lane & 15;

    // Q fragments: two 16-row tiles x 4 k-steps of 32 (16 VGPRs total).
    long qfragA[4], qfragB[4];
    {
        const unsigned char* qrowA = qp + (size_t)(rowBaseW + l15) * D_K + quad * 8;
        const unsigned char* qrowB = qrowA + 16 * D_K;
        #pragma unroll
        for (int s = 0; s < 4; ++s) {
            qfragA[s] = *reinterpret_cast<const long*>(qrowA + s * 32);
            qfragB[s] = *reinterpret_cast<const long*>(qrowB + s * 32);
        }
    }

    int qidrowA[4], qidrowB[4];
    #pragma unroll
    for (int r = 0; r < 4; ++r) {
        qidrowA[r] = qids[rowBaseW + quad * 4 + r];
        qidrowB[r] = qids[rowBaseW + 16 + quad * 4 + r];
    }

    float denA[4], numA[4], mxvA[4], mxpA[4];
    float denB[4], numB[4], mxvB[4], mxpB[4];
    #pragma unroll
    for (int r = 0; r < 4; ++r) {
        denA[r] = 0.f; numA[r] = 0.f; mxvA[r] = -INFINITY; mxpA[r] = -INFINITY;
        denB[r] = 0.f; numB[r] = 0.f; mxvB[r] = -INFINITY; mxpB[r] = -INFINITY;
    }

    const float L2E = 1.4426950408889634f;   // log2(e)
    const float CB  = 64.0f;                 // fixed exponent bias; cancels in num/den
    const int colStart = cs * 512;

    // Packed A bytes for this block's col strip: 32 tiles x 2 KB = 64 KB.
    const char* gstrip = (const char*)ap + (size_t)cs * 65536;
    const int   chunk  = wave * 2048;        // this wave's 2 KB of each 8 KB stage

    // Prologue: stage super-tile 0 into buffer 0.
    #pragma unroll
    for (int i = 0; i < 2; ++i)
        gl_lds16(gstrip + chunk + i * 1024 + lane * 16,
                 (char*)smem + chunk + i * 1024);
    __syncthreads();

    for (int t = 0; t < T_OUT; ++t) {
        const int cur = t & 1, nxt = cur ^ 1;
        // Stage t+1 (async; completes during this iteration's compute).
        if (t + 1 < T_OUT) {
            const char* gsrc = gstrip + (size_t)(t + 1) * 8192 + chunk;
            char*       ldst = (char*)smem + nxt * 8192 + chunk;
            #pragma unroll
            for (int i = 0; i < 2; ++i)
                gl_lds16(gsrc + i * 1024 + lane * 16, ldst + i * 1024);
        }

        // Compute from buffer cur: 4 sub-tiles of 16 cols x 4 k-steps,
        // each B-fragment pair feeds BOTH row-tiles (8 MFMAs / 2 ds_reads).
        const unsigned char* lbase = smem + cur * 8192 + lane * 16;
        #pragma unroll
        for (int u = 0; u < 4; ++u) {
            lx2 b01 = *reinterpret_cast<const lx2*>(lbase + u * 2048);
            lx2 b23 = *reinterpret_cast<const lx2*>(lbase + u * 2048 + 1024);

            f32x4 accA = {0.f, 0.f, 0.f, 0.f};
            f32x4 accB = {0.f, 0.f, 0.f, 0.f};
            accA = __builtin_amdgcn_mfma_f32_16x16x32_fp8_fp8(qfragA[0], b01[0], accA, 0, 0, 0);
            accB = __builtin_amdgcn_mfma_f32_16x16x32_fp8_fp8(qfragB[0], b01[0], accB, 0, 0, 0);
            accA = __builtin_amdgcn_mfma_f32_16x16x32_fp8_fp8(qfragA[1], b01[1], accA, 0, 0, 0);
            accB = __builtin_amdgcn_mfma_f32_16x16x32_fp8_fp8(qfragB[1], b01[1], accB, 0, 0, 0);
            accA = __builtin_amdgcn_mfma_f32_16x16x32_fp8_fp8(qfragA[2], b23[0], accA, 0, 0, 0);
            accB = __builtin_amdgcn_mfma_f32_16x16x32_fp8_fp8(qfragB[2], b23[0], accB, 0, 0, 0);
            accA = __builtin_amdgcn_mfma_f32_16x16x32_fp8_fp8(qfragA[3], b23[1], accA, 0, 0, 0);
            accB = __builtin_amdgcn_mfma_f32_16x16x32_fp8_fp8(qfragB[3], b23[1], accB, 0, 0, 0);

            const int c  = colStart + t * 64 + u * 16 + l15;
            const int qc = qids[c];
            const float wc = 1.0f - 0.1f * ranks[c];
            #pragma unroll
            for (int r = 0; r < 4; ++r) {
                float sv = accA[r];
                float e  = __builtin_amdgcn_exp2f(fmaf(sv, L2E, -CB));
                bool pos = (qc == qidrowA[r]);
                denA[r] += e;
                numA[r] = fmaf(pos ? wc : 0.0f, e, numA[r]);
                mxvA[r] = fmaxf(mxvA[r], sv);
                mxpA[r] = fmaxf(mxpA[r], pos ? sv : -INFINITY);
            }
            #pragma unroll
            for (int r = 0; r < 4; ++r) {
                float sv = accB[r];
                float e  = __builtin_amdgcn_exp2f(fmaf(sv, L2E, -CB));
                bool pos = (qc == qidrowB[r]);
                denB[r] += e;
                numB[r] = fmaf(pos ? wc : 0.0f, e, numB[r]);
                mxvB[r] = fmaxf(mxvB[r], sv);
                mxpB[r] = fmaxf(mxpB[r], pos ? sv : -INFINITY);
            }
        }
        __syncthreads();   // reads of cur done + stage of nxt done
    }

    // Reduce across the 16 lanes of each quad (same rows, different cols).
    #pragma unroll
    for (int m = 1; m <= 8; m <<= 1) {
        #pragma unroll
        for (int r = 0; r < 4; ++r) {
            denA[r] += __shfl_xor(denA[r], m, 64);
            numA[r] += __shfl_xor(numA[r], m, 64);
            mxvA[r]  = fmaxf(mxvA[r], __shfl_xor(mxvA[r], m, 64));
            mxpA[r]  = fmaxf(mxpA[r], __shfl_xor(mxpA[r], m, 64));
            denB[r] += __shfl_xor(denB[r], m, 64);
            numB[r] += __shfl_xor(numB[r], m, 64);
            mxvB[r]  = fmaxf(mxvB[r], __shfl_xor(mxvB[r], m, 64));
            mxpB[r]  = fmaxf(mxpB[r], __shfl_xor(mxpB[r], m, 64));
        }
    }

    if (l15 == 0) {   // lanes 0,16,32,48: write 8 rows each (wave-exclusive rows)
        const int rb = cs * B_N + rowBaseW + quad * 4;
        #pragma unroll
        for (int r = 0; r < 4; ++r) {
            pden[rb + r]       = denA[r];
            pnum[rb + r]       = numA[r];
            pmax[rb + r]       = mxvA[r];
            pmaxp[rb + r]      = mxpA[r];
            pden[rb + 16 + r]  = denB[r];
            pnum[rb + 16 + r]  = numB[r];
            pmax[rb + 16 + r]  = mxvB[r];
            pmaxp[rb + 16 + r] = mxpB[r];
        }
    }
}

// Finalize: 32 blocks x 256 threads, one row per thread (coalesced partial reads),
// block-reduce, atomicAdd into d_out (zeroed by cvt_kernel).
__launch_bounds__(256, 4)
__global__ void fin_kernel(const float* __restrict__ pden, const float* __restrict__ pnum,
                           const float* __restrict__ pmax, const float* __restrict__ pmaxp,
                           float* __restrict__ out) {
    const int r = blockIdx.x * 256 + threadIdx.x;
    float d = 0.f, n = 0.f, mv = -INFINITY, mp = -INFINITY;
    #pragma unroll
    for (int cs = 0; cs < CSPLIT; ++cs) {
        d += pden[cs * B_N + r];
        n += pnum[cs * B_N + r];
        mv = fmaxf(mv, pmax[cs * B_N + r]);
        mp = fmaxf(mp, pmaxp[cs * B_N + r]);
    }
    float lsum = -logf(n / d + 1e-8f);
    float csum = (mp == mv) ? 1.0f : 0.0f;   // argmax col positive <=> pos-max == global max
    #pragma unroll
    for (int m = 1; m <= 32; m <<= 1) {
        lsum += __shfl_xor(lsum, m, 64);
        csum += __shfl_xor(csum, m, 64);
    }
    __shared__ float sl[4], sc[4];
    const int wave = threadIdx.x >> 6;
    if ((threadIdx.x & 63) == 0) { sl[wave] = lsum; sc[wave] = csum; }
    __syncthreads();
    if (threadIdx.x == 0) {
        float L = sl[0] + sl[1] + sl[2] + sl[3];
        float C = sc[0] + sc[1] + sc[2] + sc[3];
        atomicAdd(&out[0], L * (1.0f / B_N));
        atomicAdd(&out[1], C * (1.0f / B_N));
    }
}

extern "C" void kernel_launch(void* const* d_in, const int* in_sizes, int n_in,
                              void* d_out, int out_size, void* d_ws, size_t ws_size,
                              hipStream_t stream) {
    const float* q     = (const float*)d_in[0];
    const float* a     = (const float*)d_in[1];
    const int*   qids  = (const int*)d_in[2];
    const float* ranks = (const float*)d_in[3];
    float* out = (float*)d_out;

    unsigned char* qp = (unsigned char*)d_ws;                       // 1 MB fp8 Q (row-major)
    unsigned char* ap = qp + (size_t)B_N * D_K;                     // 1 MB fp8 A (packed)
    char* p = (char*)(ap + (size_t)B_N * D_K);
    float* pden  = (float*)p;                p += CSPLIT * B_N * sizeof(float);
    float* pnum  = (float*)p;                p += CSPLIT * B_N * sizeof(float);
    float* pmax  = (float*)p;                p += CSPLIT * B_N * sizeof(float);
    float* pmaxp = (float*)p;

    cvt_kernel<<<(B_N * D_K / 8) / 256, 256, 0, stream>>>(q, a, qp, ap, out);
    mpl_part_kernel<<<(B_N / ROWS) * CSPLIT, 256, 0, stream>>>(qp, ap, qids, ranks,
                                                               pden, pnum, pmax, pmaxp);
    fin_kernel<<<B_N / 256, 256, 0, stream>>>(pden, pnum, pmax, pmaxp, out);
}

// Round 4
// 107.933 us; speedup vs baseline: 1.0334x; 1.0334x over previous
//
#include <hip/hip_runtime.h>
#include <cmath>

#define B_N 8192
#define D_K 128
#define WROWS 32           // rows per wave (2 x 16-row MFMA tiles)
#define BROWS 64           // rows per block (2 waves x 32)
#define CSPLIT 16          // column splits; each wave covers 512 cols
#define NTILE 32           // 16-col B-tiles per strip: 512/16

typedef float f32x4 __attribute__((ext_vector_type(4)));
typedef long  lx2   __attribute__((ext_vector_type(2)));

// Convert fp32 Q and A to fp8 e4m3 (OCP, via v_cvt_pk_fp8_f32 — R7-verified,
// absmax 2.4e-4). Q: row-major fp8 (byte g*8). A: packed for 16x16x32 fp8 B-op:
// per 16-col tile T, k-pair p in {0,1}: 1 KB region at T*2048 + p*1024; lane
// L = quad*16+e holds 16 B at L*16 = A[col=T*16+e][k=(2p)*32+quad*8..+7] ++
// A[col][k=(2p+1)*32+quad*8..+7]. This IS the MFMA B-fragment layout, so the
// GEMM kernel loads fragments straight from global (A is 1 MB, L2-resident;
// per-cs strip 64 KB pinned to one XCD by cs<->blockIdx%8).
// Also zeroes d_out (harness re-poisons to 0xAA before every replay).
__global__ void cvt_kernel(const float* __restrict__ q, const float* __restrict__ a,
                           unsigned char* __restrict__ qp, unsigned char* __restrict__ ap,
                           float* __restrict__ out) {
    const int g = blockIdx.x * blockDim.x + threadIdx.x;   // 0 .. B*D/8-1
    if (g < 2) out[g] = 0.0f;

    float4 q0 = reinterpret_cast<const float4*>(q)[g * 2];
    float4 q1 = reinterpret_cast<const float4*>(q)[g * 2 + 1];
    float4 a0 = reinterpret_cast<const float4*>(a)[g * 2];
    float4 a1 = reinterpret_cast<const float4*>(a)[g * 2 + 1];

    int qw0 = __builtin_amdgcn_cvt_pk_fp8_f32(q0.x, q0.y, 0, false);
    qw0     = __builtin_amdgcn_cvt_pk_fp8_f32(q0.z, q0.w, qw0, true);
    int qw1 = __builtin_amdgcn_cvt_pk_fp8_f32(q1.x, q1.y, 0, false);
    qw1     = __builtin_amdgcn_cvt_pk_fp8_f32(q1.z, q1.w, qw1, true);
    int aw0 = __builtin_amdgcn_cvt_pk_fp8_f32(a0.x, a0.y, 0, false);
    aw0     = __builtin_amdgcn_cvt_pk_fp8_f32(a0.z, a0.w, aw0, true);
    int aw1 = __builtin_amdgcn_cvt_pk_fp8_f32(a1.x, a1.y, 0, false);
    aw1     = __builtin_amdgcn_cvt_pk_fp8_f32(a1.z, a1.w, aw1, true);

    // Q row-major fp8
    *reinterpret_cast<int2*>(qp + (size_t)g * 8) = make_int2(qw0, qw1);

    // A fragment-packed fp8
    const int col = g >> 4, sq = g & 15;       // k = sq*8 .. +7
    const int s = sq >> 2, quad = sq & 3;      // k-step of 32, quad within step
    const int T = col >> 4, e = col & 15;
    const size_t off = (size_t)T * 2048 + (size_t)(s >> 1) * 1024
                     + (size_t)(quad * 16 + e) * 16 + (size_t)(s & 1) * 8;
    *reinterpret_cast<int2*>(ap + off) = make_int2(aw0, aw1);
}

// R4 structural change: NO LDS, NO barriers. R2 vs R3 showed identical totals
// (111.0/111.5) despite halved ds_reads and doubled MFMA-per-B-read -> the cost
// was the stage/barrier cadence (vmcnt(0)+s_barrier full drain per 8KB stage),
// not the compute. A is 1 MB / 64 KB per strip = L2-resident (strip pinned to
// one XCD via cs<->blockIdx%8), so B-fragments are loaded DIRECTLY from global
// with coalesced dwordx4 (cvt layout == fragment layout). Latency hiding is
// pure TLP: 2-wave blocks, 8 blocks/CU (grid 2048) = 16 waves/CU = 4/SIMD,
// plus unroll-2 load-ahead ILP. Each wave owns 32 rows (2 row-tiles: 8 MFMA
// per B-fragment pair, halves L2 B-traffic to ~3.2 us/CU).
// Floors/CU: MFMA 8.4us, VALU ~7us (separate pipes, overlap), L2 ~3.2us.
// Col enumeration c = colStart + u*16 + l15 matches R0-R3 order exactly ->
// absmax must remain 2.441e-4.
// MFMA 16x16x32 fp8_fp8 (R7-verified lane mapping):
//   A-op: lane holds A[m=lane&15][k=(lane>>4)*8+j] (8 B); B-op transposed same;
//   C/D : col=lane&15, row=(lane>>4)*4+reg.
// Sentinels: VGPR ~100-115 (<=128, NO scratch), LDS_Block_Size 0,
//            WRITE_SIZE ~2 MB, SQ_LDS_BANK_CONFLICT 0.
__launch_bounds__(128, 4)
__global__ void mpl_part_kernel(const unsigned char* __restrict__ qp,
                                const unsigned char* __restrict__ ap,
                                const int* __restrict__ qids,
                                const float* __restrict__ ranks,
                                float* __restrict__ pden, float* __restrict__ pnum,
                                float* __restrict__ pmax, float* __restrict__ pmaxp) {
    const int tid  = threadIdx.x;
    const int lane = tid & 63;
    const int wave = tid >> 6;               // 0..1
    const int rg   = blockIdx.x >> 4;        // 0..127 (64-row window)
    const int cs   = blockIdx.x & 15;        // 0..15 (cs&7 == XCD id under %8 dispatch)
    const int rowBaseW = rg * BROWS + wave * WROWS;   // this wave's 32-row window
    const int quad = lane >> 4;              // 0..3
    const int l15  = lane & 15;

    // Q fragments: two 16-row tiles x 4 k-steps of 32 (16 VGPRs total).
    long qfragA[4], qfragB[4];
    {
        const unsigned char* qrowA = qp + (size_t)(rowBaseW + l15) * D_K + quad * 8;
        const unsigned char* qrowB = qrowA + 16 * D_K;
        #pragma unroll
        for (int s = 0; s < 4; ++s) {
            qfragA[s] = *reinterpret_cast<const long*>(qrowA + s * 32);
            qfragB[s] = *reinterpret_cast<const long*>(qrowB + s * 32);
        }
    }

    int qidrowA[4], qidrowB[4];
    #pragma unroll
    for (int r = 0; r < 4; ++r) {
        qidrowA[r] = qids[rowBaseW + quad * 4 + r];
        qidrowB[r] = qids[rowBaseW + 16 + quad * 4 + r];
    }

    float denA[4], numA[4], mxvA[4], mxpA[4];
    float denB[4], numB[4], mxvB[4], mxpB[4];
    #pragma unroll
    for (int r = 0; r < 4; ++r) {
        denA[r] = 0.f; numA[r] = 0.f; mxvA[r] = -INFINITY; mxpA[r] = -INFINITY;
        denB[r] = 0.f; numB[r] = 0.f; mxvB[r] = -INFINITY; mxpB[r] = -INFINITY;
    }

    const float L2E = 1.4426950408889634f;   // log2(e)
    const float CB  = 64.0f;                 // fixed exponent bias; cancels in num/den
    const int colStart = cs * 512;

    // Packed A bytes for this wave's col strip: 32 tiles x 2 KB = 64 KB (L2-hot).
    const char* strip = (const char*)ap + (size_t)cs * 65536 + lane * 16;

    // Sweep 32 B-tiles straight from global. unroll 2 => next tile's loads
    // issue during current tile's MFMA+epilogue (no barrier ever drains them).
    #pragma unroll 2
    for (int u = 0; u < NTILE; ++u) {
        lx2 b01 = *reinterpret_cast<const lx2*>(strip + u * 2048);
        lx2 b23 = *reinterpret_cast<const lx2*>(strip + u * 2048 + 1024);

        f32x4 accA = {0.f, 0.f, 0.f, 0.f};
        f32x4 accB = {0.f, 0.f, 0.f, 0.f};
        accA = __builtin_amdgcn_mfma_f32_16x16x32_fp8_fp8(qfragA[0], b01[0], accA, 0, 0, 0);
        accB = __builtin_amdgcn_mfma_f32_16x16x32_fp8_fp8(qfragB[0], b01[0], accB, 0, 0, 0);
        accA = __builtin_amdgcn_mfma_f32_16x16x32_fp8_fp8(qfragA[1], b01[1], accA, 0, 0, 0);
        accB = __builtin_amdgcn_mfma_f32_16x16x32_fp8_fp8(qfragB[1], b01[1], accB, 0, 0, 0);
        accA = __builtin_amdgcn_mfma_f32_16x16x32_fp8_fp8(qfragA[2], b23[0], accA, 0, 0, 0);
        accB = __builtin_amdgcn_mfma_f32_16x16x32_fp8_fp8(qfragB[2], b23[0], accB, 0, 0, 0);
        accA = __builtin_amdgcn_mfma_f32_16x16x32_fp8_fp8(qfragA[3], b23[1], accA, 0, 0, 0);
        accB = __builtin_amdgcn_mfma_f32_16x16x32_fp8_fp8(qfragB[3], b23[1], accB, 0, 0, 0);

        const int c  = colStart + u * 16 + l15;
        const int qc = qids[c];
        const float wc = 1.0f - 0.1f * ranks[c];
        #pragma unroll
        for (int r = 0; r < 4; ++r) {
            float sv = accA[r];
            float e  = __builtin_amdgcn_exp2f(fmaf(sv, L2E, -CB));
            bool pos = (qc == qidrowA[r]);
            denA[r] += e;
            numA[r] = fmaf(pos ? wc : 0.0f, e, numA[r]);
            mxvA[r] = fmaxf(mxvA[r], sv);
            mxpA[r] = fmaxf(mxpA[r], pos ? sv : -INFINITY);
        }
        #pragma unroll
        for (int r = 0; r < 4; ++r) {
            float sv = accB[r];
            float e  = __builtin_amdgcn_exp2f(fmaf(sv, L2E, -CB));
            bool pos = (qc == qidrowB[r]);
            denB[r] += e;
            numB[r] = fmaf(pos ? wc : 0.0f, e, numB[r]);
            mxvB[r] = fmaxf(mxvB[r], sv);
            mxpB[r] = fmaxf(mxpB[r], pos ? sv : -INFINITY);
        }
    }

    // Reduce across the 16 lanes of each quad (same rows, different cols).
    #pragma unroll
    for (int m = 1; m <= 8; m <<= 1) {
        #pragma unroll
        for (int r = 0; r < 4; ++r) {
            denA[r] += __shfl_xor(denA[r], m, 64);
            numA[r] += __shfl_xor(numA[r], m, 64);
            mxvA[r]  = fmaxf(mxvA[r], __shfl_xor(mxvA[r], m, 64));
            mxpA[r]  = fmaxf(mxpA[r], __shfl_xor(mxpA[r], m, 64));
            denB[r] += __shfl_xor(denB[r], m, 64);
            numB[r] += __shfl_xor(numB[r], m, 64);
            mxvB[r]  = fmaxf(mxvB[r], __shfl_xor(mxvB[r], m, 64));
            mxpB[r]  = fmaxf(mxpB[r], __shfl_xor(mxpB[r], m, 64));
        }
    }

    if (l15 == 0) {   // lanes 0,16,32,48: write 8 rows each (wave-exclusive rows)
        const int rb = cs * B_N + rowBaseW + quad * 4;
        #pragma unroll
        for (int r = 0; r < 4; ++r) {
            pden[rb + r]       = denA[r];
            pnum[rb + r]       = numA[r];
            pmax[rb + r]       = mxvA[r];
            pmaxp[rb + r]      = mxpA[r];
            pden[rb + 16 + r]  = denB[r];
            pnum[rb + 16 + r]  = numB[r];
            pmax[rb + 16 + r]  = mxvB[r];
            pmaxp[rb + 16 + r] = mxpB[r];
        }
    }
}

// Finalize: 32 blocks x 256 threads, one row per thread (coalesced partial reads),
// block-reduce, atomicAdd into d_out (zeroed by cvt_kernel).
__launch_bounds__(256, 4)
__global__ void fin_kernel(const float* __restrict__ pden, const float* __restrict__ pnum,
                           const float* __restrict__ pmax, const float* __restrict__ pmaxp,
                           float* __restrict__ out) {
    const int r = blockIdx.x * 256 + threadIdx.x;
    float d = 0.f, n = 0.f, mv = -INFINITY, mp = -INFINITY;
    #pragma unroll
    for (int cs = 0; cs < CSPLIT; ++cs) {
        d += pden[cs * B_N + r];
        n += pnum[cs * B_N + r];
        mv = fmaxf(mv, pmax[cs * B_N + r]);
        mp = fmaxf(mp, pmaxp[cs * B_N + r]);
    }
    float lsum = -logf(n / d + 1e-8f);
    float csum = (mp == mv) ? 1.0f : 0.0f;   // argmax col positive <=> pos-max == global max
    #pragma unroll
    for (int m = 1; m <= 32; m <<= 1) {
        lsum += __shfl_xor(lsum, m, 64);
        csum += __shfl_xor(csum, m, 64);
    }
    __shared__ float sl[4], sc[4];
    const int wave = threadIdx.x >> 6;
    if ((threadIdx.x & 63) == 0) { sl[wave] = lsum; sc[wave] = csum; }
    __syncthreads();
    if (threadIdx.x == 0) {
        float L = sl[0] + sl[1] + sl[2] + sl[3];
        float C = sc[0] + sc[1] + sc[2] + sc[3];
        atomicAdd(&out[0], L * (1.0f / B_N));
        atomicAdd(&out[1], C * (1.0f / B_N));
    }
}

extern "C" void kernel_launch(void* const* d_in, const int* in_sizes, int n_in,
                              void* d_out, int out_size, void* d_ws, size_t ws_size,
                              hipStream_t stream) {
    const float* q     = (const float*)d_in[0];
    const float* a     = (const float*)d_in[1];
    const int*   qids  = (const int*)d_in[2];
    const float* ranks = (const float*)d_in[3];
    float* out = (float*)d_out;

    unsigned char* qp = (unsigned char*)d_ws;                       // 1 MB fp8 Q (row-major)
    unsigned char* ap = qp + (size_t)B_N * D_K;                     // 1 MB fp8 A (packed)
    char* p = (char*)(ap + (size_t)B_N * D_K);
    float* pden  = (float*)p;                p += CSPLIT * B_N * sizeof(float);
    float* pnum  = (float*)p;                p += CSPLIT * B_N * sizeof(float);
    float* pmax  = (float*)p;                p += CSPLIT * B_N * sizeof(float);
    float* pmaxp = (float*)p;

    cvt_kernel<<<(B_N * D_K / 8) / 256, 256, 0, stream>>>(q, a, qp, ap, out);
    mpl_part_kernel<<<(B_N / BROWS) * CSPLIT, 128, 0, stream>>>(qp, ap, qids, ranks,
                                                                pden, pnum, pmax, pmaxp);
    fin_kernel<<<B_N / 256, 256, 0, stream>>>(pden, pnum, pmax, pmaxp, out);
}

// Round 5
// 95.431 us; speedup vs baseline: 1.1687x; 1.1310x over previous
//
#include <hip/hip_runtime.h>
#include <cmath>

#define B_N 8192
#define D_K 128
#define ROWS 64            // rows per block; wave w owns rows [w*16, +16)
#define CSPLIT 8           // column splits; block covers 1024 cols
#define T_OUT 8            // 128-col super-tiles per block: 1024/128 (fp8: 16KB stage)

typedef float f32x4 __attribute__((ext_vector_type(4)));
typedef long  lx2   __attribute__((ext_vector_type(2)));

typedef __attribute__((address_space(3))) unsigned int as3_uint;
typedef __attribute__((address_space(1))) unsigned int as1_uint;

// Async global->LDS DMA, 16 B/lane. HW dest = wave-uniform base + lane*16
// (pattern correctness-verified R9-R13, absmax 0.0).
__device__ __forceinline__ void gl_lds16(const void* g, void* l) {
    __builtin_amdgcn_global_load_lds((const as1_uint*)(uintptr_t)g,
                                     (as3_uint*)(unsigned int)(uintptr_t)l,
                                     16, 0, 0);
}

// Convert fp32 Q and A to fp8 e4m3 (OCP, via v_cvt_pk_fp8_f32 — R7-verified,
// absmax 2.4e-4). Q: row-major fp8 (byte g*8). A: packed for 16x16x32 fp8 B-op:
// per 16-col tile T, k-pair p in {0,1}: 1 KB region at T*2048 + p*1024; lane
// L = quad*16+e holds 16 B at L*16 = A[col=T*16+e][k=(2p)*32+quad*8..+7] ++
// A[col][k=(2p+1)*32+quad*8..+7]. 8 consecutive tiles (16 KB) = one LDS stage.
// Also zeroes d_out (harness re-poisons to 0xAA before every replay).
__global__ void cvt_kernel(const float* __restrict__ q, const float* __restrict__ a,
                           unsigned char* __restrict__ qp, unsigned char* __restrict__ ap,
                           float* __restrict__ out) {
    const int g = blockIdx.x * blockDim.x + threadIdx.x;   // 0 .. B*D/8-1
    if (g < 2) out[g] = 0.0f;

    float4 q0 = reinterpret_cast<const float4*>(q)[g * 2];
    float4 q1 = reinterpret_cast<const float4*>(q)[g * 2 + 1];
    float4 a0 = reinterpret_cast<const float4*>(a)[g * 2];
    float4 a1 = reinterpret_cast<const float4*>(a)[g * 2 + 1];

    int qw0 = __builtin_amdgcn_cvt_pk_fp8_f32(q0.x, q0.y, 0, false);
    qw0     = __builtin_amdgcn_cvt_pk_fp8_f32(q0.z, q0.w, qw0, true);
    int qw1 = __builtin_amdgcn_cvt_pk_fp8_f32(q1.x, q1.y, 0, false);
    qw1     = __builtin_amdgcn_cvt_pk_fp8_f32(q1.z, q1.w, qw1, true);
    int aw0 = __builtin_amdgcn_cvt_pk_fp8_f32(a0.x, a0.y, 0, false);
    aw0     = __builtin_amdgcn_cvt_pk_fp8_f32(a0.z, a0.w, aw0, true);
    int aw1 = __builtin_amdgcn_cvt_pk_fp8_f32(a1.x, a1.y, 0, false);
    aw1     = __builtin_amdgcn_cvt_pk_fp8_f32(a1.z, a1.w, aw1, true);

    // Q row-major fp8
    *reinterpret_cast<int2*>(qp + (size_t)g * 8) = make_int2(qw0, qw1);

    // A fragment-packed fp8
    const int col = g >> 4, sq = g & 15;       // k = sq*8 .. +7
    const int s = sq >> 2, quad = sq & 3;      // k-step of 32, quad within step
    const int T = col >> 4, e = col & 15;
    const size_t off = (size_t)T * 2048 + (size_t)(s >> 1) * 1024
                     + (size_t)(quad * 16 + e) * 16 + (size_t)(s & 1) * 8;
    *reinterpret_cast<int2*>(ap + off) = make_int2(aw0, aw1);
}

// Block (rg, cs): rows [rg*64,+64) over cols [cs*1024,+1024). 4 waves; wave w owns
// rows [rg*64 + w*16, +16); all waves sweep the same cols via LDS-shared B-tiles.
// R5 = R0's proven 95.5µs skeleton (CSPLIT=8, 16KB stages, grid 1024 — R2/R3/R4's
// structural replacements all regressed 12-16µs) + two LOCAL ILP edits:
//  (1) MFMA chain split 4-dep -> 2x 2-dep independent chains (acc1 k0-63,
//      acc2 k64-127; summed in epilogue). Reassociates fp32 K-sum (~1 ulp).
//  (2) qids/ranks loads hoisted to a per-stage preamble (qc8/wc8 regs, fully
//      unrolled) -> no mid-subtile vmem dependency; loads overlap stage DMA.
// Double-buffered LDS (2 x 16 KB); stage t+1 issued after the barrier publishing t.
// MFMA 16x16x32 fp8_fp8 (R7-verified lane mapping, absmax 2.4e-4):
//   A-op: lane holds A[m=lane&15][k=(lane>>4)*8+j] (8 B); B-op transposed same;
//   C/D : col=lane&15, row=(lane>>4)*4+reg.
// Sentinels: VGPR ~70-80 (NO scratch), WRITE_SIZE ~1 MB, SQ_LDS_BANK_CONFLICT ~0.
__launch_bounds__(256, 4)
__global__ void mpl_part_kernel(const unsigned char* __restrict__ qp,
                                const unsigned char* __restrict__ ap,
                                const int* __restrict__ qids,
                                const float* __restrict__ ranks,
                                float* __restrict__ pden, float* __restrict__ pnum,
                                float* __restrict__ pmax, float* __restrict__ pmaxp) {
    __shared__ unsigned char smem[2 * 16384];   // 2 x 16 KB

    const int tid  = threadIdx.x;
    const int lane = tid & 63;
    const int wave = tid >> 6;               // 0..3
    const int rg   = blockIdx.x >> 3;        // 0..127
    const int cs   = blockIdx.x & 7;         // 0..7 (== XCD id under %8 dispatch)
    const int rowBase = rg * ROWS;
    const int quad = lane >> 4;              // 0..3
    const int l15  = lane & 15;

    // Q fragments: this wave's 16-row tile x 4 k-steps of 32 (8 VGPRs).
    long qfrag[4];
    {
        const unsigned char* qrow = qp + (size_t)(rowBase + wave * 16 + l15) * D_K + quad * 8;
        #pragma unroll
        for (int s = 0; s < 4; ++s)
            qfrag[s] = *reinterpret_cast<const long*>(qrow + s * 32);
    }

    int qidrow[4];
    #pragma unroll
    for (int r = 0; r < 4; ++r)
        qidrow[r] = qids[rowBase + wave * 16 + quad * 4 + r];

    float den[4], num[4], mxv[4], mxp[4];
    #pragma unroll
    for (int r = 0; r < 4; ++r) {
        den[r] = 0.f; num[r] = 0.f; mxv[r] = -INFINITY; mxp[r] = -INFINITY;
    }

    const float L2E = 1.4426950408889634f;   // log2(e)
    const float CB  = 64.0f;                 // fixed exponent bias; cancels in num/den
    const int colStart = cs * 1024;

    // Packed A bytes for this block's col strip: 64 tiles x 2 KB = 128 KB.
    const char* gstrip = (const char*)ap + (size_t)cs * 131072;
    const int   chunk  = wave * 4096;        // this wave's 4 KB of each 16 KB stage

    // Prologue: stage super-tile 0 into buffer 0.
    #pragma unroll
    for (int i = 0; i < 4; ++i)
        gl_lds16(gstrip + chunk + i * 1024 + lane * 16,
                 (char*)smem + chunk + i * 1024);
    __syncthreads();

    for (int t = 0; t < T_OUT; ++t) {
        const int cur = t & 1, nxt = cur ^ 1;
        // Stage t+1 (async; completes during this iteration's compute).
        if (t + 1 < T_OUT) {
            const char* gsrc = gstrip + (size_t)(t + 1) * 16384 + chunk;
            char*       ldst = (char*)smem + nxt * 16384 + chunk;
            #pragma unroll
            for (int i = 0; i < 4; ++i)
                gl_lds16(gsrc + i * 1024 + lane * 16, ldst + i * 1024);
        }

        // Per-stage column metadata preamble: 16 loads issue here, results
        // consumed per-u below; fully unrolled -> registers (no dyn indexing).
        int   qc8[8];
        float wc8[8];
        #pragma unroll
        for (int u = 0; u < 8; ++u) {
            const int c = colStart + t * 128 + u * 16 + l15;
            qc8[u] = qids[c];
            wc8[u] = 1.0f - 0.1f * ranks[c];
        }

        // Compute from buffer cur: 8 sub-tiles of 16 cols x 4 k-steps.
        // Two independent 2-deep MFMA chains per sub-tile (k0-63 / k64-127).
        const unsigned char* lbase = smem + cur * 16384 + lane * 16;
        #pragma unroll
        for (int u = 0; u < 8; ++u) {
            lx2 b01 = *reinterpret_cast<const lx2*>(lbase + u * 2048);
            lx2 b23 = *reinterpret_cast<const lx2*>(lbase + u * 2048 + 1024);

            f32x4 acc1 = {0.f, 0.f, 0.f, 0.f};
            f32x4 acc2 = {0.f, 0.f, 0.f, 0.f};
            acc1 = __builtin_amdgcn_mfma_f32_16x16x32_fp8_fp8(qfrag[0], b01[0], acc1, 0, 0, 0);
            acc2 = __builtin_amdgcn_mfma_f32_16x16x32_fp8_fp8(qfrag[2], b23[0], acc2, 0, 0, 0);
            acc1 = __builtin_amdgcn_mfma_f32_16x16x32_fp8_fp8(qfrag[1], b01[1], acc1, 0, 0, 0);
            acc2 = __builtin_amdgcn_mfma_f32_16x16x32_fp8_fp8(qfrag[3], b23[1], acc2, 0, 0, 0);

            const int   qc = qc8[u];
            const float wc = wc8[u];
            #pragma unroll
            for (int r = 0; r < 4; ++r) {
                float sv = acc1[r] + acc2[r];
                float e  = __builtin_amdgcn_exp2f(fmaf(sv, L2E, -CB));
                bool pos = (qc == qidrow[r]);
                den[r] += e;
                num[r] = fmaf(pos ? wc : 0.0f, e, num[r]);
                mxv[r] = fmaxf(mxv[r], sv);
                mxp[r] = fmaxf(mxp[r], pos ? sv : -INFINITY);
            }
        }
        __syncthreads();   // reads of cur done + stage of nxt done
    }

    // Reduce across the 16 lanes of each quad (same rows, different cols).
    #pragma unroll
    for (int m = 1; m <= 8; m <<= 1) {
        #pragma unroll
        for (int r = 0; r < 4; ++r) {
            den[r] += __shfl_xor(den[r], m, 64);
            num[r] += __shfl_xor(num[r], m, 64);
            mxv[r]  = fmaxf(mxv[r], __shfl_xor(mxv[r], m, 64));
            mxp[r]  = fmaxf(mxp[r], __shfl_xor(mxp[r], m, 64));
        }
    }

    if (l15 == 0) {   // lanes 0,16,32,48: write 4 rows each (wave-exclusive rows)
        const int rb = cs * B_N + rowBase + wave * 16 + quad * 4;
        #pragma unroll
        for (int r = 0; r < 4; ++r) {
            pden[rb + r]  = den[r];
            pnum[rb + r]  = num[r];
            pmax[rb + r]  = mxv[r];
            pmaxp[rb + r] = mxp[r];
        }
    }
}

// Finalize: 32 blocks x 256 threads, one row per thread (coalesced partial reads),
// block-reduce, atomicAdd into d_out (zeroed by cvt_kernel).
__launch_bounds__(256, 4)
__global__ void fin_kernel(const float* __restrict__ pden, const float* __restrict__ pnum,
                           const float* __restrict__ pmax, const float* __restrict__ pmaxp,
                           float* __restrict__ out) {
    const int r = blockIdx.x * 256 + threadIdx.x;
    float d = 0.f, n = 0.f, mv = -INFINITY, mp = -INFINITY;
    #pragma unroll
    for (int cs = 0; cs < CSPLIT; ++cs) {
        d += pden[cs * B_N + r];
        n += pnum[cs * B_N + r];
        mv = fmaxf(mv, pmax[cs * B_N + r]);
        mp = fmaxf(mp, pmaxp[cs * B_N + r]);
    }
    float lsum = -logf(n / d + 1e-8f);
    float csum = (mp == mv) ? 1.0f : 0.0f;   // argmax col positive <=> pos-max == global max
    #pragma unroll
    for (int m = 1; m <= 32; m <<= 1) {
        lsum += __shfl_xor(lsum, m, 64);
        csum += __shfl_xor(csum, m, 64);
    }
    __shared__ float sl[4], sc[4];
    const int wave = threadIdx.x >> 6;
    if ((threadIdx.x & 63) == 0) { sl[wave] = lsum; sc[wave] = csum; }
    __syncthreads();
    if (threadIdx.x == 0) {
        float L = sl[0] + sl[1] + sl[2] + sl[3];
        float C = sc[0] + sc[1] + sc[2] + sc[3];
        atomicAdd(&out[0], L * (1.0f / B_N));
        atomicAdd(&out[1], C * (1.0f / B_N));
    }
}

extern "C" void kernel_launch(void* const* d_in, const int* in_sizes, int n_in,
                              void* d_out, int out_size, void* d_ws, size_t ws_size,
                              hipStream_t stream) {
    const float* q     = (const float*)d_in[0];
    const float* a     = (const float*)d_in[1];
    const int*   qids  = (const int*)d_in[2];
    const float* ranks = (const float*)d_in[3];
    float* out = (float*)d_out;

    unsigned char* qp = (unsigned char*)d_ws;                       // 1 MB fp8 Q (row-major)
    unsigned char* ap = qp + (size_t)B_N * D_K;                     // 1 MB fp8 A (packed)
    char* p = (char*)(ap + (size_t)B_N * D_K);
    float* pden  = (float*)p;                p += CSPLIT * B_N * sizeof(float);
    float* pnum  = (float*)p;                p += CSPLIT * B_N * sizeof(float);
    float* pmax  = (float*)p;                p += CSPLIT * B_N * sizeof(float);
    float* pmaxp = (float*)p;

    cvt_kernel<<<(B_N * D_K / 8) / 256, 256, 0, stream>>>(q, a, qp, ap, out);
    mpl_part_kernel<<<(B_N / ROWS) * CSPLIT, 256, 0, stream>>>(qp, ap, qids, ranks,
                                                               pden, pnum, pmax, pmaxp);
    fin_kernel<<<B_N / 256, 256, 0, stream>>>(pden, pnum, pmax, pmaxp, out);
}